// Round 4
// baseline (734.733 us; speedup 1.0000x reference)
//
#include <hip/hip_runtime.h>
#include <cstdint>
#include <cstddef>

// ---------------------------------------------------------------------------
// Types
// ---------------------------------------------------------------------------
typedef __attribute__((ext_vector_type(8))) short  short8;   // 8 x bf16 bits (4 VGPRs)
typedef __attribute__((ext_vector_type(4))) float  floatx4;  // MFMA acc
typedef __attribute__((ext_vector_type(4))) unsigned short ushort4v;

__device__ __forceinline__ unsigned short f2b(float f) {
  unsigned u = __builtin_bit_cast(unsigned, f);
  u = u + 0x7fffu + ((u >> 16) & 1u);   // RNE
  return (unsigned short)(u >> 16);
}
__device__ __forceinline__ float b2f(unsigned short h) {
  unsigned u = ((unsigned)h) << 16;
  return __builtin_bit_cast(float, u);
}

// async global->LDS, 16B per lane. LDS dest is wave-uniform base + lane*16.
__device__ __forceinline__ void gld_lds16(const void* g, void* l) {
  __builtin_amdgcn_global_load_lds(
      (const __attribute__((address_space(1))) unsigned int*)g,
      (__attribute__((address_space(3))) unsigned int*)l,
      16, 0, 0);
}

// ---------------------------------------------------------------------------
// Fused fp32 -> bf16 cast for all 5 tensors (one launch instead of five).
// i is a float4 index over the concatenation [x | wq | wk | wv | wo].
// ---------------------------------------------------------------------------
__global__ void __launch_bounds__(256) f2b_multi(const float* __restrict__ x,
                                                 const float* __restrict__ wq,
                                                 const float* __restrict__ wk,
                                                 const float* __restrict__ wv,
                                                 const float* __restrict__ wo,
                                                 unsigned short* __restrict__ xb,
                                                 unsigned short* __restrict__ wqb,
                                                 unsigned short* __restrict__ wkb,
                                                 unsigned short* __restrict__ wvb,
                                                 unsigned short* __restrict__ wob) {
  int i = blockIdx.x * 256 + threadIdx.x;    // < 12582912
  const float* in; unsigned short* out; int off;
  if      (i <  2097152) { in = x;  out = xb;  off = 0;       }
  else if (i <  6291456) { in = wq; out = wqb; off = 2097152; }
  else if (i <  7340032) { in = wk; out = wkb; off = 6291456; }
  else if (i <  8388608) { in = wv; out = wvb; off = 7340032; }
  else                   { in = wo; out = wob; off = 8388608; }
  const int k = i - off;
  floatx4 v = ((const floatx4*)in)[k];
  ushort4v o;
  o[0] = f2b(v[0]); o[1] = f2b(v[1]); o[2] = f2b(v[2]); o[3] = f2b(v[3]);
  ((ushort4v*)out)[k] = o;
}

// ---------------------------------------------------------------------------
// GEMM: C[M,N] = A[M,K] @ B[N,K]^T   (A,B bf16 row-major K-contiguous)
// 128x128 block tile, 4 waves each 64x64 (4x4 of 16x16x32 MFMA), BK=32.
//
// A: staged in LDS (double-buffered 2 x 8 KB), coalesced 64B-per-row chunks
//    with octet-rotation swizzle (round-3 proven, 0 bank conflicts).
// B: DIRECT global->register fragments. For B^T layout the fragment
//    (row = n_frag + l15, k = kt + quad*8) makes each global_load_dwordx4
//    cover 16 rows x 64 contiguous bytes -> perfectly coalesced. This halves
//    LDS-pipe traffic (the measured bottleneck) and removes one barrier:
//    the single __syncthreads' vmcnt drain waits on loads issued a full
//    iteration earlier (prefetch pipeline), hiding the m97 barrier stall.
//
// MODE: 1 = fp32 out, 2 = bf16 out + fused RoPE on cols < 5120.
// ---------------------------------------------------------------------------
template <int MODE>
__global__ void __launch_bounds__(256) gemm_bt(const unsigned short* __restrict__ A,
                                               const unsigned short* __restrict__ B,
                                               float* __restrict__ Cf,
                                               unsigned short* __restrict__ Cb,
                                               int M, int N, int K,
                                               const float* __restrict__ fc,
                                               const float* __restrict__ fs) {
  __shared__ __align__(16) unsigned short As[2][4096];  // [buf][128 rows][32 k] swizzled
  const int m0 = blockIdx.x * 128;
  const int n0 = blockIdx.y * 128;
  const int tid  = threadIdx.x;
  const int wave = tid >> 6, lane = tid & 63;
  const int quad = lane >> 4, l15 = lane & 15;
  const int wm = ((wave >> 1) & 1) * 64;
  const int wn = (wave & 1) * 64;

  floatx4 acc[4][4] = {};

  // A staging: instr i = wave*2+t covers rows i*16..i*16+15; lane l ->
  // row i*16+(l>>2), physical octet slot l&3, global octet (slot-(row>>1))&3.
  const int lr = lane >> 2, sj = lane & 3;
  const unsigned short* pa[2];
  int laoff[2];
#pragma unroll
  for (int t = 0; t < 2; ++t) {
    const int i = wave * 2 + t;
    const int r = i * 16 + lr;
    const int o = (sj - (r >> 1)) & 3;
    pa[t] = A + (size_t)(m0 + r) * K + o * 8;
    laoff[t] = i * 512;
  }

  // B direct-fragment pointers (one per tn tile)
  const unsigned short* pb[4];
#pragma unroll
  for (int tn = 0; tn < 4; ++tn)
    pb[tn] = B + (size_t)(n0 + wn + tn * 16 + l15) * K + quad * 8;

  // prologue: stage A(0) into buf 0; prefetch B(0) into registers
  gld_lds16(pa[0], &As[0][laoff[0]]);
  gld_lds16(pa[1], &As[0][laoff[1]]);
  short8 bcur[4];
#pragma unroll
  for (int tn = 0; tn < 4; ++tn) bcur[tn] = *(const short8*)pb[tn];

  const int niter = K >> 5;
  for (int j = 0; j < niter; ++j) {
    __syncthreads();   // A(j)/B(j) loads drained; buf (j+1)&1 free for DMA
    const int ktn = (j + 1) << 5;
    if (j + 1 < niter) {
      gld_lds16(pa[0] + ktn, &As[(j + 1) & 1][laoff[0]]);
      gld_lds16(pa[1] + ktn, &As[(j + 1) & 1][laoff[1]]);
    }
    // A fragments from LDS buf j&1 (swizzled octet)
    short8 af[4];
#pragma unroll
    for (int t = 0; t < 4; ++t) {
      const int rA = wm + t * 16 + l15;
      const int ja = (quad + (rA >> 1)) & 3;
      af[t] = *(const short8*)&As[j & 1][rA * 32 + ja * 8];
    }
    // prefetch B(j+1) into registers (consumed next iteration)
    short8 bnext[4];
    if (j + 1 < niter) {
#pragma unroll
      for (int tn = 0; tn < 4; ++tn) bnext[tn] = *(const short8*)(pb[tn] + ktn);
    }
#pragma unroll
    for (int tm = 0; tm < 4; ++tm)
#pragma unroll
      for (int tn = 0; tn < 4; ++tn)
        acc[tm][tn] = __builtin_amdgcn_mfma_f32_16x16x32_bf16(af[tm], bcur[tn], acc[tm][tn], 0, 0, 0);
#pragma unroll
    for (int tn = 0; tn < 4; ++tn) bcur[tn] = bnext[tn];
  }

  // epilogue: C/D layout col = lane&15, row = quad*4 + reg
  // MODE==2: fused RoPE. col parity == l15 parity; pair partner = lane^1.
#pragma unroll
  for (int tm = 0; tm < 4; ++tm) {
#pragma unroll
    for (int tn = 0; tn < 4; ++tn) {
      const int colb = n0 + wn + tn * 16;            // wave-uniform
      const int col  = colb + l15;
      const bool rope = (MODE == 2) && (colb < 5120);
      const int p = (col & 127) >> 1;
      const float sgn = (l15 & 1) ? 1.f : -1.f;
#pragma unroll
      for (int r = 0; r < 4; ++r) {
        const int row = m0 + wm + tm * 16 + quad * 4 + r;
        float v = acc[tm][tn][r];
        if (rope) {
          const float partner = __shfl_xor(v, 1);
          const float c  = fc[row * 64 + p];
          const float sn = fs[row * 64 + p];
          v = v * c + partner * sn * sgn;
        }
        if (MODE == 1) Cf[(size_t)row * N + col] = v;
        else           Cb[(size_t)row * N + col] = f2b(v);
      }
    }
  }
}

// ---------------------------------------------------------------------------
// bf16 tiled transpose
// ---------------------------------------------------------------------------
__global__ void __launch_bounds__(256) transpose_bf16(const unsigned short* __restrict__ in,
                                                      unsigned short* __restrict__ out,
                                                      int R, int C, int in_stride) {
  __shared__ __align__(16) unsigned short tile[64][72];
  const int br = blockIdx.y * 64;
  const int bc = blockIdx.x * 64;
  const int tid = threadIdx.x;
  const int lr = tid >> 3;
  const int lc = (tid & 7) * 8;
#pragma unroll
  for (int it = 0; it < 2; ++it) {
    const int r = it * 32 + lr;
    *(short8*)&tile[r][lc] = *(const short8*)(in + (size_t)(br + r) * in_stride + bc + lc);
  }
  __syncthreads();
#pragma unroll
  for (int it = 0; it < 2; ++it) {
    const int c = it * 32 + lr;
    short8 v;
#pragma unroll
    for (int j = 0; j < 8; ++j) v[j] = (short)tile[lc + j][c];
    *(short8*)(out + (size_t)(bc + c) * R + br + lc) = v;
  }
}

// ---------------------------------------------------------------------------
// Flash attention v2 (causal, GQA 4:1). S=2048, D=128, 32 heads.
// 64-row q-tiles; block handles the PAIR (bx, 31-bx) -> exactly 33 k-tiles
// per block (perfect balance). 4 waves x 16 q-rows. K-tiles of 64 keys.
// Double-buffered K/V staging; prefetch issued right after the publishing
// barrier so global->LDS latency overlaps the whole compute of tile j.
// ---------------------------------------------------------------------------
#define SL2E 0.1275500406721347f   /* (1/sqrt(128)) * log2(e) */

__global__ void __launch_bounds__(256) flash_attn(const unsigned short* __restrict__ Q,  // (2048,6144)
                                                  const unsigned short* __restrict__ Kp, // (2048,6144)+off
                                                  const unsigned short* __restrict__ Vt, // (1024,2048)
                                                  unsigned short* __restrict__ O) {      // (2048,4096)
  constexpr int QS = 6144;
  const int bx  = blockIdx.x;      // 0..15 -> tiles bx and 31-bx
  const int h   = blockIdx.y;
  const int kvh = h >> 2;
  const int tid = threadIdx.x;
  const int wave = tid >> 6, lane = tid & 63;
  const int quad = lane >> 4, l15 = lane & 15;

  __shared__ __align__(16) unsigned short Ks[2][8192];   // 16 dc x 64 key x 8
  __shared__ __align__(16) unsigned short Vs[2][8192];   // 8 sc x 128 d x 8
  __shared__ __align__(16) unsigned short Ps[4][16 * 76];
  unsigned short* Pw = Ps[wave];

  const int i0 = wave * 4;
  const unsigned short* kbase = Kp + kvh * 128;
  const unsigned short* vbase[4];
  int vslot_sc[4];
#pragma unroll
  for (int ii = 0; ii < 4; ++ii) {
    const int i = i0 + ii;
    const int slot = i * 64 + lane;
    const int sc = slot >> 7, d = slot & 127;
    vbase[ii] = Vt + (size_t)(kvh * 128 + d) * 2048;
    vslot_sc[ii] = sc * 8;
  }

  for (int seg = 0; seg < 2; ++seg) {
    const int qt  = seg ? (31 - bx) : bx;
    const int q0  = qt * 64;
    const int qra = q0 + wave * 16;
    const int n   = qt + 1;

    short8 aq[4];
#pragma unroll
    for (int ks = 0; ks < 4; ++ks)
      aq[ks] = *(const short8*)(Q + (size_t)(qra + l15) * QS + h * 128 + ks * 32 + quad * 8);

    floatx4 oacc[8] = {};
    float mrow[4], lrow[4];
#pragma unroll
    for (int r = 0; r < 4; ++r) { mrow[r] = -1e30f; lrow[r] = 0.f; }

    {
      const int cc = 0;
#pragma unroll
      for (int ii = 0; ii < 4; ++ii) {
        const int i = i0 + ii;
        gld_lds16(kbase + (size_t)(cc + lane) * QS + i * 8, &Ks[0][i * 512]);
        gld_lds16(vbase[ii] + cc + vslot_sc[ii], &Vs[0][i * 512]);
      }
    }

    for (int j = 0; j < n; ++j) {
      __syncthreads();
      if (j + 1 < n) {
        const int cc = (j + 1) * 64;
        const int nb = (j + 1) & 1;
#pragma unroll
        for (int ii = 0; ii < 4; ++ii) {
          const int i = i0 + ii;
          gld_lds16(kbase + (size_t)(cc + lane) * QS + i * 8, &Ks[nb][i * 512]);
          gld_lds16(vbase[ii] + cc + vslot_sc[ii], &Vs[nb][i * 512]);
        }
      }
      const unsigned short* kb = Ks[j & 1];
      const unsigned short* vb = Vs[j & 1];
      const int c0 = j * 64;

      floatx4 sacc[4] = {};
#pragma unroll
      for (int ks = 0; ks < 4; ++ks) {
#pragma unroll
        for (int tn = 0; tn < 4; ++tn) {
          short8 bk = *(const short8*)&kb[((ks * 4 + quad) * 64 + tn * 16 + l15) * 8];
          sacc[tn] = __builtin_amdgcn_mfma_f32_16x16x32_bf16(aq[ks], bk, sacc[tn], 0, 0, 0);
        }
      }

      const bool needmask = (c0 + 63 > qra);
#pragma unroll
      for (int r = 0; r < 4; ++r) {
        const int rowg = qra + quad * 4 + r;
        float t0 = sacc[0][r] * SL2E, t1 = sacc[1][r] * SL2E;
        float t2 = sacc[2][r] * SL2E, t3 = sacc[3][r] * SL2E;
        if (needmask) {
          t0 = (c0 +  0 + l15 <= rowg) ? t0 : -1e30f;
          t1 = (c0 + 16 + l15 <= rowg) ? t1 : -1e30f;
          t2 = (c0 + 32 + l15 <= rowg) ? t2 : -1e30f;
          t3 = (c0 + 48 + l15 <= rowg) ? t3 : -1e30f;
        }
        float mx = fmaxf(fmaxf(t0, t1), fmaxf(t2, t3));
#pragma unroll
        for (int off = 1; off < 16; off <<= 1)
          mx = fmaxf(mx, __shfl_xor(mx, off, 16));
        const float mold = mrow[r];
        const float mn   = fmaxf(mold, mx);
        const float alpha = exp2f(mold - mn);
        float p0 = exp2f(t0 - mn), p1 = exp2f(t1 - mn);
        float p2 = exp2f(t2 - mn), p3 = exp2f(t3 - mn);
        sacc[0][r] = p0; sacc[1][r] = p1; sacc[2][r] = p2; sacc[3][r] = p3;
        float lsum = (p0 + p1) + (p2 + p3);
#pragma unroll
        for (int off = 1; off < 16; off <<= 1)
          lsum += __shfl_xor(lsum, off, 16);
        mrow[r] = mn;
        lrow[r] = lrow[r] * alpha + lsum;
#pragma unroll
        for (int tn = 0; tn < 8; ++tn) oacc[tn][r] *= alpha;
      }

#pragma unroll
      for (int tn = 0; tn < 4; ++tn)
#pragma unroll
        for (int r = 0; r < 4; ++r)
          Pw[(quad * 4 + r) * 76 + tn * 16 + l15] = f2b(sacc[tn][r]);

      short8 ap[2];
#pragma unroll
      for (int k2 = 0; k2 < 2; ++k2)
        ap[k2] = *(const short8*)&Pw[l15 * 76 + k2 * 32 + quad * 8];
#pragma unroll
      for (int k2 = 0; k2 < 2; ++k2) {
#pragma unroll
        for (int tn = 0; tn < 8; ++tn) {
          short8 bv = *(const short8*)&vb[((k2 * 4 + quad) * 128 + tn * 16 + l15) * 8];
          oacc[tn] = __builtin_amdgcn_mfma_f32_16x16x32_bf16(ap[k2], bv, oacc[tn], 0, 0, 0);
        }
      }
    }

#pragma unroll
    for (int r = 0; r < 4; ++r) {
      const float inv = 1.f / lrow[r];
      const int rowg = qra + quad * 4 + r;
#pragma unroll
      for (int tn = 0; tn < 8; ++tn)
        O[(size_t)rowg * 4096 + h * 128 + tn * 16 + l15] = f2b(oacc[tn][r] * inv);
    }
    __syncthreads();
  }
}

// ---------------------------------------------------------------------------
// Host launcher
// ---------------------------------------------------------------------------
extern "C" void kernel_launch(void* const* d_in, const int* in_sizes, int n_in,
                              void* d_out, int out_size, void* d_ws, size_t ws_size,
                              hipStream_t stream) {
  const float* x  = (const float*)d_in[0];
  const float* wq = (const float*)d_in[1];
  const float* wk = (const float*)d_in[2];
  const float* wv = (const float*)d_in[3];
  const float* wo = (const float*)d_in[4];
  const float* fc = (const float*)d_in[7];
  const float* fs = (const float*)d_in[8];
  float* out = (float*)d_out;

  char* ws = (char*)d_ws;
  unsigned short* xb    = (unsigned short*)(ws + 0);          // x bf16       16 MB
  unsigned short* wqkvb = (unsigned short*)(ws + 16777216);   // wq|wk|wv     48 MB
  unsigned short* wob   = (unsigned short*)(ws + 67108864);   // wo bf16      32 MB
  unsigned short* qkv   = (unsigned short*)(ws + 100663296);  // (2048,6144)  24 MB
  unsigned short* vt    = (unsigned short*)(ws + 125829120);  // (1024,2048)   4 MB
  unsigned short* ob    = (unsigned short*)(ws + 130023424);  // (2048,4096)  16 MB
  unsigned short* wkb = wqkvb + (size_t)4096 * 4096;
  unsigned short* wvb = wkb + (size_t)1024 * 4096;

  // 1) all fp32->bf16 casts in one launch
  f2b_multi<<<49152, 256, 0, stream>>>(x, wq, wk, wv, wo, xb, wqkvb, wkb, wvb, wob);

  // 2) QKV projection with fused RoPE on Q|K columns
  gemm_bt<2><<<dim3(16, 48), 256, 0, stream>>>(xb, wqkvb, nullptr, qkv, 2048, 6144, 4096, fc, fs);

  // 3) V^T: (2048,1024) slice at col 5120 -> (1024,2048)
  transpose_bf16<<<dim3(16, 32), 256, 0, stream>>>(qkv + 5120, vt, 2048, 1024, 6144);

  // 4) flash attention -> O (2048,4096) bf16
  flash_attn<<<dim3(16, 32), 256, 0, stream>>>(qkv, qkv + 4096, vt, ob);

  // 5) output projection: O @ wo^T -> fp32 d_out
  gemm_bt<1><<<dim3(16, 32), 256, 0, stream>>>(ob, wob, out, nullptr, 2048, 4096, 4096, nullptr, nullptr);
}